// Round 3
// baseline (215.055 us; speedup 1.0000x reference)
//
#include <hip/hip_runtime.h>

#define D_ 64
#define S_ 2048
#define B_ 16
#define QT 64
#define KVT 128

typedef short short8 __attribute__((ext_vector_type(8)));
typedef short short4a __attribute__((ext_vector_type(4)));
typedef float floatx4 __attribute__((ext_vector_type(4)));
typedef unsigned uint2v __attribute__((ext_vector_type(2)));

// exp(s/sqrt(2048)) == exp2(s * SC2); SC2 is pre-folded into the K pack.
#define SC2 (1.4426950408889634f / 45.254833995939045f)

__device__ __forceinline__ unsigned short f2bf(float f) {
  unsigned u = __builtin_bit_cast(unsigned, f);
  u += 0x7fffu + ((u >> 16) & 1u);   // round-to-nearest-even
  return (unsigned short)(u >> 16);
}

// 16x16x16 bf16 MFMA: B-operand k-mapping (k=4g+j) == C-layout m-mapping (m=4g+r),
// so a packed C-fragment feeds directly as B. A: m=ln, k=4g+j.
__device__ __forceinline__ floatx4 mfma16(short4a a, short4a b, floatx4 c) {
#if __has_builtin(__builtin_amdgcn_mfma_f32_16x16x16bf16_1k)
  return __builtin_amdgcn_mfma_f32_16x16x16bf16_1k(a, b, c, 0, 0, 0);
#else
  floatx4 d;
  asm volatile("v_mfma_f32_16x16x16_bf16 %0, %1, %2, %3"
               : "=v"(d) : "v"(a), "v"(b), "v"(c));
  return d;
#endif
}

// ---------------------------------------------------------------------------
// FRAGMENT-ORDERED layouts (so attn's loads are lane-contiguous):
//   Q/K: per b, 128 row-tiles (16 rows x 64 d). Element (row,d):
//        rb=row>>4, ln=row&15, ks=d>>5, g=(d>>3)&3, j=d&7
//        addr = (b*128+rb)*1024 + ks*512 + (g*16+ln)*8 + j
//   V:   per b, 128 kv-tiles x 4 d-tiles (16 d x 16 kv). Element (d,kv):
//        kvblk=kv>>4, dblk=d>>4, ln=d&15, g=(kv>>2)&3, j=kv&3
//        addr = ((b*128+kvblk)*4+dblk)*256 + (g*16+ln)*4 + j
// ---------------------------------------------------------------------------
__global__ __launch_bounds__(256) void pack_all(const float* __restrict__ Q,
                                                const float* __restrict__ K,
                                                const float* __restrict__ V,
                                                unsigned short* __restrict__ Qp,
                                                unsigned short* __restrict__ Kp,
                                                unsigned short* __restrict__ Vt) {
  __shared__ __align__(16) unsigned short tile[256][72];
  const int t = threadIdx.x;
  const int bid = blockIdx.x;
  if (bid < 256) {
    const bool isK = bid >= 128;
    const float* src = isK ? K : Q;
    unsigned short* dst = isK ? Kp : Qp;
    const float scale = isK ? SC2 : 1.0f;
    const int rb = bid & 127;
    const int s0 = rb * 16;
#pragma unroll
    for (int i = 0; i < 16; i++) {
      int j = i * 256 + t;
      int d = j >> 6;
      int sb4 = (j & 63) * 4;
      const float4 v = *(const float4*)(src + (size_t)d * (S_ * B_) + s0 * B_ + sb4);
      float vv[4] = {v.x, v.y, v.z, v.w};
#pragma unroll
      for (int k = 0; k < 4; k++) {
        int sb = sb4 + k;                    // si = sb>>4, b = sb&15
        tile[(sb & 15) * 16 + (sb >> 4)][d] = f2bf(vv[k] * scale);
      }
    }
    __syncthreads();
#pragma unroll
    for (int i = 0; i < 8; i++) {
      int j = i * 256 + t;
      int r = j >> 3, c = j & 7;
      int b = r >> 4, si = r & 15;
      uint4 v = *(const uint4*)(&tile[r][c * 8]);
      // frag order: ks=c>>2, g=c&3, ln=si, j=0..7 contiguous -> one uint4
      *(uint4*)(dst + (((size_t)(b * 128 + rb)) << 10) + ((c >> 2) << 9) +
                (((c & 3) * 16 + si) << 3)) = v;
    }
  } else {
    const int vb = bid - 256;
    const int s0 = (vb & 31) * 64;
    const int d0 = (vb >> 5) * 16;
    const int dblk = vb >> 5;
#pragma unroll
    for (int i = 0; i < 16; i++) {
      int j = i * 256 + t;
      int dd = j >> 8;
      int sb4 = (j & 255) * 4;
      const float4 v = *(const float4*)(V + (size_t)(d0 + dd) * (S_ * B_) + s0 * B_ + sb4);
      float vv[4] = {v.x, v.y, v.z, v.w};
#pragma unroll
      for (int k = 0; k < 4; k++) {
        int sb = sb4 + k;
        tile[(sb & 15) * 16 + dd][sb >> 4] = f2bf(vv[k]);
      }
    }
    __syncthreads();
#pragma unroll
    for (int i = 0; i < 8; i++) {
      int j = i * 256 + t;
      int r = j >> 3, c = j & 7;
      int b = r >> 4, dd = r & 15;
      uint4 v = *(const uint4*)(&tile[r][c * 8]);
      // kv = s0 + c*8 + e: kvblk = (vb&31)*4 + (c>>1), g0 = (c&1)*2
      int kvblk = (vb & 31) * 4 + (c >> 1);
      int g0 = (c & 1) * 2;
      size_t a0 = (((size_t)(b * 128 + kvblk) * 4 + dblk) << 8) + ((g0 * 16 + dd) << 2);
      *(uint2*)(Vt + a0) = make_uint2(v.x, v.y);          // g0,   j=0..3
      *(uint2*)(Vt + a0 + 64) = make_uint2(v.z, v.w);     // g0+1, j=0..3
    }
  }
}

// ---------------------------------------------------------------------------
// attn: grid 1024 = 16 b x 32 q-tiles x 2 kv-halves. Each block: 8 kv tiles.
//       S^T = K.Q^T (16x16x32, frag-ordered lane-contiguous global loads);
//       P packed in-register == B-frag of 16x16x16 PV MFMA;
//       O^T_w = V^T . P^T over wave-private 32-kv slices.
//       Writes UNNORMALIZED O-partials + denominator partials; the combine
//       and divide happen in unpack_o. LDS reduction uses a 2-wave buffer
//       (36864 B) so 4 blocks/CU fit -> 4 waves/SIMD (was grid-capped at 2).
// ---------------------------------------------------------------------------
__global__ __launch_bounds__(256, 4) void attn(const unsigned short* __restrict__ Qp,
                                               const unsigned short* __restrict__ Kp,
                                               const unsigned short* __restrict__ Vt,
                                               float* __restrict__ Otp,
                                               float* __restrict__ Dp) {
  // red: [2 waves][64 q][68 d] f32 = 34816 B; lred 1 KB. Total 35840 B.
  __shared__ __align__(16) char smem_[34816 + 1024];
  float* red = (float*)smem_;
  float* lred = (float*)(smem_ + 34816);

  const int tid = threadIdx.x;
  const int w = tid >> 6, l = tid & 63, g = l >> 4, ln = l & 15;
  const int b = blockIdx.x & 15;                // XCD-pinned batch
  const int q0 = ((int)(blockIdx.x >> 4) & 31) * QT;
  const int h = (int)(blockIdx.x >> 9);         // kv half

  const unsigned short* Qb = Qp + ((size_t)b << 17);   // b * 131072
  const unsigned short* Kb = Kp + ((size_t)b << 17);
  const unsigned short* Vb = Vt + ((size_t)b << 17);

  // per-wave/lane base pointers into the fragment-ordered buffers
  const unsigned short* Qw = Qb + (((size_t)(q0 >> 4)) << 10) + l * 8;
  const unsigned short* Kw = Kb + h * 65536 + w * 2048 + l * 8;
  const unsigned short* Vw = Vb + h * 65536 + w * 2048 + l * 4;

  // Q^T B-frags (once per block): n=q=16nf+ln, k=d=32ks+8g+j
  short8 qf[4][2];
#pragma unroll
  for (int nf = 0; nf < 4; nf++)
#pragma unroll
    for (int ks = 0; ks < 2; ks++)
      qf[nf][ks] = *(const short8*)(Qw + nf * 1024 + ks * 512);

  // K frags tile 0 (wave-private kv slice rows)
  short8 kf[2][2];
#pragma unroll
  for (int mf = 0; mf < 2; mf++)
#pragma unroll
    for (int ks = 0; ks < 2; ks++)
      kf[mf][ks] = *(const short8*)(Kw + mf * 1024 + ks * 512);

  // V^T A-frags tile 0: m=d=16mfd+ln, k=kv=4g+j (+mf*16)
  short4a vf[4][2];
#pragma unroll
  for (int mfd = 0; mfd < 4; mfd++)
#pragma unroll
    for (int mf = 0; mf < 2; mf++)
      vf[mfd][mf] = *(const short4a*)(Vw + mf * 1024 + mfd * 256);

  const short4a ones = {(short)0x3F80, (short)0x3F80, (short)0x3F80, (short)0x3F80};
  floatx4 oacc[4][4];                           // [d=16mfd+4g+r][q=16nf+ln]
  floatx4 dacc[4];                              // denominator partials
#pragma unroll
  for (int mfd = 0; mfd < 4; mfd++)
#pragma unroll
    for (int nf = 0; nf < 4; nf++) oacc[mfd][nf] = (floatx4){0.f, 0.f, 0.f, 0.f};
#pragma unroll
  for (int nf = 0; nf < 4; nf++) dacc[nf] = (floatx4){0.f, 0.f, 0.f, 0.f};

  for (int t = 0; t < 8; t++) {
    const int tn = ((t + 1) & 7) * 8192;        // next tile's frag offset (wraps)

    // ---- S^T[32 kv][64 q] = K . Q^T  (pre-scaled: sacc = s*SC2) ----
    floatx4 sacc[2][4];
#pragma unroll
    for (int mf = 0; mf < 2; mf++)
#pragma unroll
      for (int nf = 0; nf < 4; nf++) sacc[mf][nf] = (floatx4){0.f, 0.f, 0.f, 0.f};
    __builtin_amdgcn_s_setprio(1);
#pragma unroll
    for (int ks = 0; ks < 2; ks++)
#pragma unroll
      for (int mf = 0; mf < 2; mf++)
#pragma unroll
        for (int nf = 0; nf < 4; nf++)
          sacc[mf][nf] = __builtin_amdgcn_mfma_f32_16x16x32_bf16(kf[mf][ks], qf[nf][ks],
                                                                 sacc[mf][nf], 0, 0, 0);
    __builtin_amdgcn_s_setprio(0);

    // prefetch K frags for next tile (coalesced: 64 lanes x 16 B contiguous)
#pragma unroll
    for (int mf = 0; mf < 2; mf++)
#pragma unroll
      for (int ks = 0; ks < 2; ks++)
        kf[mf][ks] = *(const short8*)(Kw + tn + mf * 1024 + ks * 512);

    // ---- P = exp2(sacc), packed in-register: C-frag -> B-frag (16x16x16) ----
    short4a pb[2][4];
#pragma unroll
    for (int mf = 0; mf < 2; mf++)
#pragma unroll
      for (int nf = 0; nf < 4; nf++) {
        unsigned u0 = __builtin_bit_cast(unsigned, __builtin_amdgcn_exp2f(sacc[mf][nf][0])) + 0x8000u;
        unsigned u1 = __builtin_bit_cast(unsigned, __builtin_amdgcn_exp2f(sacc[mf][nf][1])) + 0x8000u;
        unsigned u2 = __builtin_bit_cast(unsigned, __builtin_amdgcn_exp2f(sacc[mf][nf][2])) + 0x8000u;
        unsigned u3 = __builtin_bit_cast(unsigned, __builtin_amdgcn_exp2f(sacc[mf][nf][3])) + 0x8000u;
        unsigned lo = __builtin_amdgcn_perm(u1, u0, 0x07060302u);  // [bf16(e0), bf16(e1)]
        unsigned hi = __builtin_amdgcn_perm(u3, u2, 0x07060302u);  // [bf16(e2), bf16(e3)]
        pb[mf][nf] = __builtin_bit_cast(short4a, (uint2v){lo, hi});
      }

    __builtin_amdgcn_s_setprio(1);
    // ---- denominator: ones-row MFMA (colsum of P) ----
#pragma unroll
    for (int mf = 0; mf < 2; mf++)
#pragma unroll
      for (int nf = 0; nf < 4; nf++)
        dacc[nf] = mfma16(ones, pb[mf][nf], dacc[nf]);

    // ---- O^T += V^T . P^T over wave's 32 kv (2 chunks of 16) ----
#pragma unroll
    for (int mfd = 0; mfd < 4; mfd++)
#pragma unroll
      for (int mf = 0; mf < 2; mf++) {
#pragma unroll
        for (int nf = 0; nf < 4; nf++)
          oacc[mfd][nf] = mfma16(vf[mfd][mf], pb[mf][nf], oacc[mfd][nf]);
      }
    __builtin_amdgcn_s_setprio(0);

    // prefetch V frags for next tile (coalesced: 64 lanes x 8 B contiguous)
#pragma unroll
    for (int mfd = 0; mfd < 4; mfd++)
#pragma unroll
      for (int mf = 0; mf < 2; mf++)
        vf[mfd][mf] = *(const short4a*)(Vw + tn + mf * 1024 + mfd * 256);
  }

  // ---- cross-wave reduction with half-size buffer ----
  if (g == 0) {
#pragma unroll
    for (int nf = 0; nf < 4; nf++) lred[w * 64 + nf * 16 + ln] = dacc[nf][0];
  }
  if (w < 2) {
#pragma unroll
    for (int mfd = 0; mfd < 4; mfd++)
#pragma unroll
      for (int nf = 0; nf < 4; nf++)
        *(floatx4*)(&red[w * 4352 + (nf * 16 + ln) * 68 + mfd * 16 + g * 4]) = oacc[mfd][nf];
  }
  __syncthreads();
  if (w >= 2) {
#pragma unroll
    for (int mfd = 0; mfd < 4; mfd++)
#pragma unroll
      for (int nf = 0; nf < 4; nf++) {
        float* p = &red[(w - 2) * 4352 + (nf * 16 + ln) * 68 + mfd * 16 + g * 4];
        *(floatx4*)p = *(const floatx4*)p + oacc[mfd][nf];
      }
  }
  __syncthreads();

  // wave w stores d-quarter [16w,16w+16) for all 64 q (unnormalized partials)
  const int q = l;
  if (w == 0) {
    const float denom = lred[q] + lred[64 + q] + lred[128 + q] + lred[192 + q];
    Dp[(size_t)h * (B_ * S_) + (size_t)b * S_ + q0 + q] = denom;
  }
  float* Oth = Otp + (size_t)h * ((size_t)B_ * D_ * S_);
#pragma unroll
  for (int i = 0; i < 4; i++) {
    floatx4 s = *(const floatx4*)(&red[q * 68 + w * 16 + i * 4]) +
                *(const floatx4*)(&red[4352 + q * 68 + w * 16 + i * 4]);
#pragma unroll
    for (int r = 0; r < 4; r++)
      Oth[(size_t)(b * D_ + w * 16 + i * 4 + r) * S_ + q0 + q] = s[r];
  }
}

// ---------------------------------------------------------------------------
// Unpack: (Ot0+Ot1)[B][D][S] f32, scaled by 1/(D0+D1)[B][S] -> out [D][S][B].
// ---------------------------------------------------------------------------
__global__ __launch_bounds__(256) void unpack_o(const float* __restrict__ Ot0,
                                                const float* __restrict__ Ot1,
                                                const float* __restrict__ Dp0,
                                                const float* __restrict__ Dp1,
                                                float* __restrict__ out) {
  const int d0 = (int)(blockIdx.x & 7) * 8;
  const int s0 = (int)(blockIdx.x >> 3) * 64;
  __shared__ float u[8 * 1024];
  __shared__ float linv_s[1024];                // [b][si]
  const int t = threadIdx.x;
#pragma unroll
  for (int k = 0; k < 4; k++) {
    int idx = k * 256 + t;
    int bb = idx >> 6, si = idx & 63;
    float dsum = Dp0[(size_t)bb * S_ + s0 + si] + Dp1[(size_t)bb * S_ + s0 + si];
    linv_s[idx] = 1.0f / dsum;
  }
  __syncthreads();
#pragma unroll
  for (int i = 0; i < 8; i++) {
    int j = i * 256 + t;
    int d = j >> 8, bb = (j >> 4) & 15, c = j & 15;
    const size_t off = (size_t)(bb * D_ + d0 + d) * S_ + s0 + c * 4;
    float4 v0 = *(const float4*)(Ot0 + off);
    float4 v1 = *(const float4*)(Ot1 + off);
    float vv[4] = {v0.x + v1.x, v0.y + v1.y, v0.z + v1.z, v0.w + v1.w};
#pragma unroll
    for (int k = 0; k < 4; k++) {
      int si = c * 4 + k;
      int W = si * 16 + bb;
      int Wp = W ^ ((si & 15) << 2);
      u[d * 1024 + Wp] = vv[k] * linv_s[bb * 64 + si];
    }
  }
  __syncthreads();
#pragma unroll
  for (int i = 0; i < 8; i++) {
    int j = i * 256 + t;
    int d = j >> 8, c2 = j & 255;
    int G = c2 ^ ((c2 >> 2) & 15);
    float4 v = *(const float4*)(&u[d * 1024 + G * 4]);
    *(float4*)(out + (size_t)(d0 + d) * (S_ * B_) + s0 * B_ + c2 * 4) = v;
  }
}

// ---------------------------------------------------------------------------
extern "C" void kernel_launch(void* const* d_in, const int* in_sizes, int n_in,
                              void* d_out, int out_size, void* d_ws, size_t ws_size,
                              hipStream_t stream) {
  const float* Q = (const float*)d_in[0];    // f32 [D][S][B]
  const float* K = (const float*)d_in[1];
  const float* V = (const float*)d_in[2];
  float* out = (float*)d_out;                // f32 [D][S][B]
  char* ws = (char*)d_ws;
  unsigned short* Qp = (unsigned short*)(ws);                  // 4 MB bf16, frag-ordered
  unsigned short* Kp = (unsigned short*)(ws + (4u << 20));     // 4 MB bf16, frag-ordered, pre-scaled
  unsigned short* Vt = (unsigned short*)(ws + (8u << 20));     // 4 MB bf16, frag-ordered V^T
  float* Otp = (float*)(ws + (12u << 20));                     // 2 x 8 MB f32 [B][D][S] partials
  float* Dp = (float*)(ws + (28u << 20));                      // 2 x 128 KB f32 [B][S] denom partials

  hipLaunchKernelGGL(pack_all, dim3(384), dim3(256), 0, stream, Q, K, V, Qp, Kp, Vt);
  hipLaunchKernelGGL(attn, dim3(1024), dim3(256), 0, stream, Qp, Kp, Vt, Otp, Dp);
  hipLaunchKernelGGL(unpack_o, dim3(256), dim3(256), 0, stream,
                     Otp, Otp + (size_t)B_ * D_ * S_, Dp, Dp + (size_t)B_ * S_, out);
}

// Round 4
// 108.848 us; speedup vs baseline: 1.9757x; 1.9757x over previous
//
#include <hip/hip_runtime.h>

#define D_ 64
#define S_ 2048
#define B_ 16
#define QT 64
#define KVT 128

typedef short short8 __attribute__((ext_vector_type(8)));
typedef short short4a __attribute__((ext_vector_type(4)));
typedef float floatx4 __attribute__((ext_vector_type(4)));
typedef unsigned uint2v __attribute__((ext_vector_type(2)));

// exp(s/sqrt(2048)) == exp2(s * SC2); SC2 is pre-folded into the K pack.
#define SC2 (1.4426950408889634f / 45.254833995939045f)

__device__ __forceinline__ unsigned short f2bf(float f) {
  unsigned u = __builtin_bit_cast(unsigned, f);
  u += 0x7fffu + ((u >> 16) & 1u);   // round-to-nearest-even
  return (unsigned short)(u >> 16);
}

// 16x16x16 bf16 MFMA: B-operand k-mapping (k=4g+j) == C-layout m-mapping (m=4g+r),
// so a packed C-fragment feeds directly as B. A: m=ln, k=4g+j.
__device__ __forceinline__ floatx4 mfma16(short4a a, short4a b, floatx4 c) {
#if __has_builtin(__builtin_amdgcn_mfma_f32_16x16x16bf16_1k)
  return __builtin_amdgcn_mfma_f32_16x16x16bf16_1k(a, b, c, 0, 0, 0);
#else
  floatx4 d;
  asm volatile("v_mfma_f32_16x16x16_bf16 %0, %1, %2, %3"
               : "=v"(d) : "v"(a), "v"(b), "v"(c));
  return d;
#endif
}

// ---------------------------------------------------------------------------
// FRAGMENT-ORDERED layouts (so attn's loads are lane-contiguous):
//   Q/K: per b, 128 row-tiles (16 rows x 64 d). Element (row,d):
//        rb=row>>4, ln=row&15, ks=d>>5, g=(d>>3)&3, j=d&7
//        addr = (b*128+rb)*1024 + ks*512 + (g*16+ln)*8 + j
//   V:   per b, 128 kv-tiles x 4 d-tiles (16 d x 16 kv). Element (d,kv):
//        kvblk=kv>>4, dblk=d>>4, ln=d&15, g=(kv>>2)&3, j=kv&3
//        addr = ((b*128+kvblk)*4+dblk)*256 + (g*16+ln)*4 + j
// ---------------------------------------------------------------------------
__global__ __launch_bounds__(256) void pack_all(const float* __restrict__ Q,
                                                const float* __restrict__ K,
                                                const float* __restrict__ V,
                                                unsigned short* __restrict__ Qp,
                                                unsigned short* __restrict__ Kp,
                                                unsigned short* __restrict__ Vt) {
  __shared__ __align__(16) unsigned short tile[256][72];
  const int t = threadIdx.x;
  const int bid = blockIdx.x;
  if (bid < 256) {
    const bool isK = bid >= 128;
    const float* src = isK ? K : Q;
    unsigned short* dst = isK ? Kp : Qp;
    const float scale = isK ? SC2 : 1.0f;
    const int rb = bid & 127;
    const int s0 = rb * 16;
#pragma unroll
    for (int i = 0; i < 16; i++) {
      int j = i * 256 + t;
      int d = j >> 6;
      int sb4 = (j & 63) * 4;
      const float4 v = *(const float4*)(src + (size_t)d * (S_ * B_) + s0 * B_ + sb4);
      float vv[4] = {v.x, v.y, v.z, v.w};
#pragma unroll
      for (int k = 0; k < 4; k++) {
        int sb = sb4 + k;                    // si = sb>>4, b = sb&15
        tile[(sb & 15) * 16 + (sb >> 4)][d] = f2bf(vv[k] * scale);
      }
    }
    __syncthreads();
#pragma unroll
    for (int i = 0; i < 8; i++) {
      int j = i * 256 + t;
      int r = j >> 3, c = j & 7;
      int b = r >> 4, si = r & 15;
      uint4 v = *(const uint4*)(&tile[r][c * 8]);
      // frag order: ks=c>>2, g=c&3, ln=si, j=0..7 contiguous -> one uint4
      *(uint4*)(dst + (((size_t)(b * 128 + rb)) << 10) + ((c >> 2) << 9) +
                (((c & 3) * 16 + si) << 3)) = v;
    }
  } else {
    const int vb = bid - 256;
    const int s0 = (vb & 31) * 64;
    const int d0 = (vb >> 5) * 16;
    const int dblk = vb >> 5;
#pragma unroll
    for (int i = 0; i < 16; i++) {
      int j = i * 256 + t;
      int dd = j >> 8;
      int sb4 = (j & 255) * 4;
      const float4 v = *(const float4*)(V + (size_t)(d0 + dd) * (S_ * B_) + s0 * B_ + sb4);
      float vv[4] = {v.x, v.y, v.z, v.w};
#pragma unroll
      for (int k = 0; k < 4; k++) {
        int sb = sb4 + k;
        tile[(sb & 15) * 16 + dd][sb >> 4] = f2bf(vv[k]);
      }
    }
    __syncthreads();
#pragma unroll
    for (int i = 0; i < 8; i++) {
      int j = i * 256 + t;
      int r = j >> 3, c = j & 7;
      int b = r >> 4, dd = r & 15;
      uint4 v = *(const uint4*)(&tile[r][c * 8]);
      // kv = s0 + c*8 + e: kvblk = (vb&31)*4 + (c>>1), g0 = (c&1)*2
      int kvblk = (vb & 31) * 4 + (c >> 1);
      int g0 = (c & 1) * 2;
      size_t a0 = (((size_t)(b * 128 + kvblk) * 4 + dblk) << 8) + ((g0 * 16 + dd) << 2);
      *(uint2*)(Vt + a0) = make_uint2(v.x, v.y);          // g0,   j=0..3
      *(uint2*)(Vt + a0 + 64) = make_uint2(v.z, v.w);     // g0+1, j=0..3
    }
  }
}

// ---------------------------------------------------------------------------
// attn: grid 1024 = 16 b x 32 q-tiles x 2 kv-halves. Each block: 8 kv tiles.
//       S^T = K.Q^T (16x16x32, frag-ordered lane-contiguous global loads);
//       P packed in-register == B-frag of 16x16x16 PV MFMA;
//       O^T_w = V^T . P^T over wave-private 32-kv slices.
//       Writes UNNORMALIZED O-partials + denominator partials; combine+divide
//       happen in unpack_o. 2-wave LDS reduce buffer (35840 B).
//       launch_bounds min-waves=2: rounds 1-2 proved no spill at this setting
//       (96 VGPR); round 3's min-waves=4 capped regs at 128 -> 250+ MB scratch
//       spill traffic. Natural alloc ~160 regs -> 3 waves/SIMD by regfile.
// ---------------------------------------------------------------------------
__global__ __launch_bounds__(256, 2) void attn(const unsigned short* __restrict__ Qp,
                                               const unsigned short* __restrict__ Kp,
                                               const unsigned short* __restrict__ Vt,
                                               float* __restrict__ Otp,
                                               float* __restrict__ Dp) {
  // red: [2 waves][64 q][68 d] f32 = 34816 B; lred 1 KB. Total 35840 B.
  __shared__ __align__(16) char smem_[34816 + 1024];
  float* red = (float*)smem_;
  float* lred = (float*)(smem_ + 34816);

  const int tid = threadIdx.x;
  const int w = tid >> 6, l = tid & 63, g = l >> 4, ln = l & 15;
  const int b = blockIdx.x & 15;                // XCD-pinned batch
  const int q0 = ((int)(blockIdx.x >> 4) & 31) * QT;
  const int h = (int)(blockIdx.x >> 9);         // kv half

  const unsigned short* Qb = Qp + ((size_t)b << 17);   // b * 131072
  const unsigned short* Kb = Kp + ((size_t)b << 17);
  const unsigned short* Vb = Vt + ((size_t)b << 17);

  // per-wave/lane base pointers into the fragment-ordered buffers
  const unsigned short* Qw = Qb + (((size_t)(q0 >> 4)) << 10) + l * 8;
  const unsigned short* Kw = Kb + h * 65536 + w * 2048 + l * 8;
  const unsigned short* Vw = Vb + h * 65536 + w * 2048 + l * 4;

  // Q^T B-frags (once per block): n=q=16nf+ln, k=d=32ks+8g+j
  short8 qf[4][2];
#pragma unroll
  for (int nf = 0; nf < 4; nf++)
#pragma unroll
    for (int ks = 0; ks < 2; ks++)
      qf[nf][ks] = *(const short8*)(Qw + nf * 1024 + ks * 512);

  // K frags tile 0 (wave-private kv slice rows)
  short8 kf[2][2];
#pragma unroll
  for (int mf = 0; mf < 2; mf++)
#pragma unroll
    for (int ks = 0; ks < 2; ks++)
      kf[mf][ks] = *(const short8*)(Kw + mf * 1024 + ks * 512);

  // V^T A-frags tile 0: m=d=16mfd+ln, k=kv=4g+j (+mf*16)
  short4a vf[4][2];
#pragma unroll
  for (int mfd = 0; mfd < 4; mfd++)
#pragma unroll
    for (int mf = 0; mf < 2; mf++)
      vf[mfd][mf] = *(const short4a*)(Vw + mf * 1024 + mfd * 256);

  const short4a ones = {(short)0x3F80, (short)0x3F80, (short)0x3F80, (short)0x3F80};
  floatx4 oacc[4][4];                           // [d=16mfd+4g+r][q=16nf+ln]
  floatx4 dacc[4];                              // denominator partials
#pragma unroll
  for (int mfd = 0; mfd < 4; mfd++)
#pragma unroll
    for (int nf = 0; nf < 4; nf++) oacc[mfd][nf] = (floatx4){0.f, 0.f, 0.f, 0.f};
#pragma unroll
  for (int nf = 0; nf < 4; nf++) dacc[nf] = (floatx4){0.f, 0.f, 0.f, 0.f};

  for (int t = 0; t < 8; t++) {
    const int tn = ((t + 1) & 7) * 8192;        // next tile's frag offset (wraps)

    // ---- S^T[32 kv][64 q] = K . Q^T  (pre-scaled: sacc = s*SC2) ----
    floatx4 sacc[2][4];
#pragma unroll
    for (int mf = 0; mf < 2; mf++)
#pragma unroll
      for (int nf = 0; nf < 4; nf++) sacc[mf][nf] = (floatx4){0.f, 0.f, 0.f, 0.f};
    __builtin_amdgcn_s_setprio(1);
#pragma unroll
    for (int ks = 0; ks < 2; ks++)
#pragma unroll
      for (int mf = 0; mf < 2; mf++)
#pragma unroll
        for (int nf = 0; nf < 4; nf++)
          sacc[mf][nf] = __builtin_amdgcn_mfma_f32_16x16x32_bf16(kf[mf][ks], qf[nf][ks],
                                                                 sacc[mf][nf], 0, 0, 0);
    __builtin_amdgcn_s_setprio(0);

    // prefetch K frags for next tile (coalesced: 64 lanes x 16 B contiguous)
#pragma unroll
    for (int mf = 0; mf < 2; mf++)
#pragma unroll
      for (int ks = 0; ks < 2; ks++)
        kf[mf][ks] = *(const short8*)(Kw + tn + mf * 1024 + ks * 512);

    // ---- P = exp2(sacc), packed in-register: C-frag -> B-frag (16x16x16) ----
    short4a pb[2][4];
#pragma unroll
    for (int mf = 0; mf < 2; mf++)
#pragma unroll
      for (int nf = 0; nf < 4; nf++) {
        unsigned u0 = __builtin_bit_cast(unsigned, __builtin_amdgcn_exp2f(sacc[mf][nf][0])) + 0x8000u;
        unsigned u1 = __builtin_bit_cast(unsigned, __builtin_amdgcn_exp2f(sacc[mf][nf][1])) + 0x8000u;
        unsigned u2 = __builtin_bit_cast(unsigned, __builtin_amdgcn_exp2f(sacc[mf][nf][2])) + 0x8000u;
        unsigned u3 = __builtin_bit_cast(unsigned, __builtin_amdgcn_exp2f(sacc[mf][nf][3])) + 0x8000u;
        unsigned lo = __builtin_amdgcn_perm(u1, u0, 0x07060302u);  // [bf16(e0), bf16(e1)]
        unsigned hi = __builtin_amdgcn_perm(u3, u2, 0x07060302u);  // [bf16(e2), bf16(e3)]
        pb[mf][nf] = __builtin_bit_cast(short4a, (uint2v){lo, hi});
      }

    __builtin_amdgcn_s_setprio(1);
    // ---- denominator: ones-row MFMA (colsum of P) ----
#pragma unroll
    for (int mf = 0; mf < 2; mf++)
#pragma unroll
      for (int nf = 0; nf < 4; nf++)
        dacc[nf] = mfma16(ones, pb[mf][nf], dacc[nf]);

    // ---- O^T += V^T . P^T over wave's 32 kv (2 chunks of 16) ----
#pragma unroll
    for (int mfd = 0; mfd < 4; mfd++)
#pragma unroll
      for (int mf = 0; mf < 2; mf++) {
#pragma unroll
        for (int nf = 0; nf < 4; nf++)
          oacc[mfd][nf] = mfma16(vf[mfd][mf], pb[mf][nf], oacc[mfd][nf]);
      }
    __builtin_amdgcn_s_setprio(0);

    // prefetch V frags for next tile (coalesced: 64 lanes x 8 B contiguous)
#pragma unroll
    for (int mfd = 0; mfd < 4; mfd++)
#pragma unroll
      for (int mf = 0; mf < 2; mf++)
        vf[mfd][mf] = *(const short4a*)(Vw + tn + mf * 1024 + mfd * 256);
  }

  // ---- cross-wave reduction with half-size buffer ----
  if (g == 0) {
#pragma unroll
    for (int nf = 0; nf < 4; nf++) lred[w * 64 + nf * 16 + ln] = dacc[nf][0];
  }
  if (w < 2) {
#pragma unroll
    for (int mfd = 0; mfd < 4; mfd++)
#pragma unroll
      for (int nf = 0; nf < 4; nf++)
        *(floatx4*)(&red[w * 4352 + (nf * 16 + ln) * 68 + mfd * 16 + g * 4]) = oacc[mfd][nf];
  }
  __syncthreads();
  if (w >= 2) {
#pragma unroll
    for (int mfd = 0; mfd < 4; mfd++)
#pragma unroll
      for (int nf = 0; nf < 4; nf++) {
        float* p = &red[(w - 2) * 4352 + (nf * 16 + ln) * 68 + mfd * 16 + g * 4];
        *(floatx4*)p = *(const floatx4*)p + oacc[mfd][nf];
      }
  }
  __syncthreads();

  // wave w stores d-quarter [16w,16w+16) for all 64 q (unnormalized partials)
  const int q = l;
  if (w == 0) {
    const float denom = lred[q] + lred[64 + q] + lred[128 + q] + lred[192 + q];
    Dp[(size_t)h * (B_ * S_) + (size_t)b * S_ + q0 + q] = denom;
  }
  float* Oth = Otp + (size_t)h * ((size_t)B_ * D_ * S_);
#pragma unroll
  for (int i = 0; i < 4; i++) {
    floatx4 s = *(const floatx4*)(&red[q * 68 + w * 16 + i * 4]) +
                *(const floatx4*)(&red[4352 + q * 68 + w * 16 + i * 4]);
#pragma unroll
    for (int r = 0; r < 4; r++)
      Oth[(size_t)(b * D_ + w * 16 + i * 4 + r) * S_ + q0 + q] = s[r];
  }
}

// ---------------------------------------------------------------------------
// Unpack: (Ot0+Ot1)[B][D][S] f32, scaled by 1/(D0+D1)[B][S] -> out [D][S][B].
// ---------------------------------------------------------------------------
__global__ __launch_bounds__(256) void unpack_o(const float* __restrict__ Ot0,
                                                const float* __restrict__ Ot1,
                                                const float* __restrict__ Dp0,
                                                const float* __restrict__ Dp1,
                                                float* __restrict__ out) {
  const int d0 = (int)(blockIdx.x & 7) * 8;
  const int s0 = (int)(blockIdx.x >> 3) * 64;
  __shared__ float u[8 * 1024];
  __shared__ float linv_s[1024];                // [b][si]
  const int t = threadIdx.x;
#pragma unroll
  for (int k = 0; k < 4; k++) {
    int idx = k * 256 + t;
    int bb = idx >> 6, si = idx & 63;
    float dsum = Dp0[(size_t)bb * S_ + s0 + si] + Dp1[(size_t)bb * S_ + s0 + si];
    linv_s[idx] = 1.0f / dsum;
  }
  __syncthreads();
#pragma unroll
  for (int i = 0; i < 8; i++) {
    int j = i * 256 + t;
    int d = j >> 8, bb = (j >> 4) & 15, c = j & 15;
    const size_t off = (size_t)(bb * D_ + d0 + d) * S_ + s0 + c * 4;
    float4 v0 = *(const float4*)(Ot0 + off);
    float4 v1 = *(const float4*)(Ot1 + off);
    float vv[4] = {v0.x + v1.x, v0.y + v1.y, v0.z + v1.z, v0.w + v1.w};
#pragma unroll
    for (int k = 0; k < 4; k++) {
      int si = c * 4 + k;
      int W = si * 16 + bb;
      int Wp = W ^ ((si & 15) << 2);
      u[d * 1024 + Wp] = vv[k] * linv_s[bb * 64 + si];
    }
  }
  __syncthreads();
#pragma unroll
  for (int i = 0; i < 8; i++) {
    int j = i * 256 + t;
    int d = j >> 8, c2 = j & 255;
    int G = c2 ^ ((c2 >> 2) & 15);
    float4 v = *(const float4*)(&u[d * 1024 + G * 4]);
    *(float4*)(out + (size_t)(d0 + d) * (S_ * B_) + s0 * B_ + c2 * 4) = v;
  }
}

// ---------------------------------------------------------------------------
extern "C" void kernel_launch(void* const* d_in, const int* in_sizes, int n_in,
                              void* d_out, int out_size, void* d_ws, size_t ws_size,
                              hipStream_t stream) {
  const float* Q = (const float*)d_in[0];    // f32 [D][S][B]
  const float* K = (const float*)d_in[1];
  const float* V = (const float*)d_in[2];
  float* out = (float*)d_out;                // f32 [D][S][B]
  char* ws = (char*)d_ws;
  unsigned short* Qp = (unsigned short*)(ws);                  // 4 MB bf16, frag-ordered
  unsigned short* Kp = (unsigned short*)(ws + (4u << 20));     // 4 MB bf16, frag-ordered, pre-scaled
  unsigned short* Vt = (unsigned short*)(ws + (8u << 20));     // 4 MB bf16, frag-ordered V^T
  float* Otp = (float*)(ws + (12u << 20));                     // 2 x 8 MB f32 [B][D][S] partials
  float* Dp = (float*)(ws + (28u << 20));                      // 2 x 128 KB f32 [B][S] denom partials

  hipLaunchKernelGGL(pack_all, dim3(384), dim3(256), 0, stream, Q, K, V, Qp, Kp, Vt);
  hipLaunchKernelGGL(attn, dim3(1024), dim3(256), 0, stream, Qp, Kp, Vt, Otp, Dp);
  hipLaunchKernelGGL(unpack_o, dim3(256), dim3(256), 0, stream,
                     Otp, Otp + (size_t)B_ * D_ * S_, Dp, Dp + (size_t)B_ * S_, out);
}

// Round 5
// 100.000 us; speedup vs baseline: 2.1505x; 1.0885x over previous
//
#include <hip/hip_runtime.h>

#define D_ 64
#define S_ 2048
#define B_ 16
#define QT 64
#define KVT 128

typedef short short8 __attribute__((ext_vector_type(8)));
typedef short short4a __attribute__((ext_vector_type(4)));
typedef float floatx4 __attribute__((ext_vector_type(4)));
typedef unsigned uint2v __attribute__((ext_vector_type(2)));
typedef unsigned uint4v __attribute__((ext_vector_type(4)));

// exp(s/sqrt(2048)) == exp2(s * SC2); SC2 is pre-folded into the K pack.
#define SC2 (1.4426950408889634f / 45.254833995939045f)

__device__ __forceinline__ unsigned short f2bf(float f) {
  unsigned u = __builtin_bit_cast(unsigned, f);
  u += 0x7fffu + ((u >> 16) & 1u);   // round-to-nearest-even
  return (unsigned short)(u >> 16);
}

// ---------------------------------------------------------------------------
// FRAGMENT-ORDERED layouts (so attn's loads are lane-contiguous):
//   Q/K: per b, 128 row-tiles (16 rows x 64 d). Element (row,d):
//        rb=row>>4, ln=row&15, ks=d>>5, g=(d>>3)&3, j=d&7
//        addr = (b*128+rb)*1024 + ks*512 + (g*16+ln)*8 + j
//   V (k-PERMUTED for x32 PV): per b, 64 kv-chunks (32 kv) x 4 dblk.
//        Lane l=(g,ln), elem e: d = dblk*16+ln, kv = c32*32 + perm(g,e),
//        perm(g,e) = e<4 ? 4g+e : 16+4g+(e-4)
//        addr = ((b*64+c32)*4+dblk)*512 + l*8 + e
//        This matches the PV B-frag built from two packed QK C-frags
//        (k-slot 8g+j == kv perm(g,j) on BOTH operands -> result invariant).
// ---------------------------------------------------------------------------
__global__ __launch_bounds__(256) void pack_all(const float* __restrict__ Q,
                                                const float* __restrict__ K,
                                                const float* __restrict__ V,
                                                unsigned short* __restrict__ Qp,
                                                unsigned short* __restrict__ Kp,
                                                unsigned short* __restrict__ Vt) {
  __shared__ __align__(16) unsigned short tile[256][72];
  const int t = threadIdx.x;
  const int bid = blockIdx.x;
  if (bid < 256) {
    const bool isK = bid >= 128;
    const float* src = isK ? K : Q;
    unsigned short* dst = isK ? Kp : Qp;
    const float scale = isK ? SC2 : 1.0f;
    const int rb = bid & 127;
    const int s0 = rb * 16;
#pragma unroll
    for (int i = 0; i < 16; i++) {
      int j = i * 256 + t;
      int d = j >> 6;
      int sb4 = (j & 63) * 4;
      const float4 v = *(const float4*)(src + (size_t)d * (S_ * B_) + s0 * B_ + sb4);
      float vv[4] = {v.x, v.y, v.z, v.w};
#pragma unroll
      for (int k = 0; k < 4; k++) {
        int sb = sb4 + k;                    // si = sb>>4, b = sb&15
        tile[(sb & 15) * 16 + (sb >> 4)][d] = f2bf(vv[k] * scale);
      }
    }
    __syncthreads();
#pragma unroll
    for (int i = 0; i < 8; i++) {
      int j = i * 256 + t;
      int r = j >> 3, c = j & 7;
      int b = r >> 4, si = r & 15;
      uint4 v = *(const uint4*)(&tile[r][c * 8]);
      // frag order: ks=c>>2, g=c&3, ln=si, j=0..7 contiguous -> one uint4
      *(uint4*)(dst + (((size_t)(b * 128 + rb)) << 10) + ((c >> 2) << 9) +
                (((c & 3) * 16 + si) << 3)) = v;
    }
  } else {
    const int vb = bid - 256;
    const int s0 = (vb & 31) * 64;           // 64 kv per block
    const int d0 = (vb >> 5) * 16;
    const int dblk = vb >> 5;
#pragma unroll
    for (int i = 0; i < 16; i++) {
      int j = i * 256 + t;
      int dd = j >> 8;
      int sb4 = (j & 255) * 4;
      const float4 v = *(const float4*)(V + (size_t)(d0 + dd) * (S_ * B_) + s0 * B_ + sb4);
      float vv[4] = {v.x, v.y, v.z, v.w};
#pragma unroll
      for (int k = 0; k < 4; k++) {
        int sb = sb4 + k;
        tile[(sb & 15) * 16 + dd][sb >> 4] = f2bf(vv[k]);  // row=b*16+dd, col=kv(0..63)
      }
    }
    __syncthreads();
    // write k-permuted A-frags: per (b, c32in{0,1}, lane l): 8 shorts
#pragma unroll
    for (int i = 0; i < 8; i++) {
      int j = i * 256 + t;                   // [0,2048)
      int b = j >> 7;
      int c32r = (j >> 6) & 1;
      int l = j & 63, g = l >> 4, ln = l & 15;
      const unsigned short* row = &tile[b * 16 + ln][c32r * 32];
      uint2 u0 = *(const uint2*)(row + g * 4);        // kv 4g..4g+3
      uint2 u1 = *(const uint2*)(row + 16 + g * 4);   // kv 16+4g..16+4g+3
      int c32 = (s0 >> 5) + c32r;
      uint4 o = make_uint4(u0.x, u0.y, u1.x, u1.y);
      *(uint4*)(Vt + (((size_t)(b * 64 + c32) * 4 + dblk) << 9) + l * 8) = o;
    }
  }
}

// ---------------------------------------------------------------------------
// attn: S^T = K.Q^T (16x16x32, frag-ordered lane-contiguous global loads);
//       P packed in-register; PV + denominator ALSO on native 16x16x32 via
//       k-permutation (B-frag = concat of two packed C-frags, V pre-permuted
//       to match) -- replaces 40 legacy 16x16x16 MFMAs/chunk with 20 x32.
//       O^T_w = V^T . P^T over wave-private 32-kv slices; one LDS reduction.
//       NO barriers in the main loop.
// ---------------------------------------------------------------------------
__global__ __launch_bounds__(256, 2) void attn(const unsigned short* __restrict__ Qp,
                                               const unsigned short* __restrict__ Kp,
                                               const unsigned short* __restrict__ Vt,
                                               float* __restrict__ Ot) {
  // red: [4 waves][64 q][68 d] f32 = 69632 B; lred 1 KB.
  __shared__ __align__(16) char smem_[69632 + 1024];
  float* red = (float*)smem_;
  float* lred = (float*)(smem_ + 69632);

  const int tid = threadIdx.x;
  const int w = tid >> 6, l = tid & 63, g = l >> 4, ln = l & 15;
  const int b = blockIdx.x & 15;                // XCD-pinned batch
  const int q0 = (int)(blockIdx.x >> 4) * QT;

  const unsigned short* Qb = Qp + ((size_t)b << 17);   // b * 131072
  const unsigned short* Kb = Kp + ((size_t)b << 17);
  const unsigned short* Vb = Vt + ((size_t)b << 17);

  // per-wave/lane base pointers into the fragment-ordered buffers
  const unsigned short* Qw = Qb + (((size_t)(q0 >> 4)) << 10) + l * 8;
  const unsigned short* Kw = Kb + w * 2048 + l * 8;    // wave's 2 row-tiles/128-kv
  const unsigned short* Vw = Vb + w * 2048 + l * 8;    // wave's c32 (=t*4+w) x 4 dblk

  // Q^T B-frags (once per block): n=q=16nf+ln, k=d=32ks+8g+j
  short8 qf[4][2];
#pragma unroll
  for (int nf = 0; nf < 4; nf++)
#pragma unroll
    for (int ks = 0; ks < 2; ks++)
      qf[nf][ks] = *(const short8*)(Qw + nf * 1024 + ks * 512);

  // K frags tile 0 (wave-private kv slice rows)
  short8 kf[2][2];
#pragma unroll
  for (int mf = 0; mf < 2; mf++)
#pragma unroll
    for (int ks = 0; ks < 2; ks++)
      kf[mf][ks] = *(const short8*)(Kw + mf * 1024 + ks * 512);

  // V^T A-frags tile 0 (k-permuted layout): m=d=16mfd+ln, k-slot 8g+j
  short8 vf[4];
#pragma unroll
  for (int mfd = 0; mfd < 4; mfd++)
    vf[mfd] = *(const short8*)(Vw + mfd * 512);

  const short8 ones8 = {(short)0x3F80, (short)0x3F80, (short)0x3F80, (short)0x3F80,
                        (short)0x3F80, (short)0x3F80, (short)0x3F80, (short)0x3F80};
  floatx4 oacc[4][4];                           // [d=16mfd+4g+r][q=16nf+ln]
  floatx4 dacc[4];                              // denominator partials (rows equal)
#pragma unroll
  for (int mfd = 0; mfd < 4; mfd++)
#pragma unroll
    for (int nf = 0; nf < 4; nf++) oacc[mfd][nf] = (floatx4){0.f, 0.f, 0.f, 0.f};
#pragma unroll
  for (int nf = 0; nf < 4; nf++) dacc[nf] = (floatx4){0.f, 0.f, 0.f, 0.f};

  for (int t = 0; t < 16; t++) {
    const int tn = ((t + 1) & 15) * 8192;       // next tile's frag offset (wraps)

    // ---- S^T[32 kv][64 q] = K . Q^T  (pre-scaled: sacc = s*SC2) ----
    floatx4 sacc[2][4];
#pragma unroll
    for (int mf = 0; mf < 2; mf++)
#pragma unroll
      for (int nf = 0; nf < 4; nf++) sacc[mf][nf] = (floatx4){0.f, 0.f, 0.f, 0.f};
    __builtin_amdgcn_s_setprio(1);
#pragma unroll
    for (int ks = 0; ks < 2; ks++)
#pragma unroll
      for (int mf = 0; mf < 2; mf++)
#pragma unroll
        for (int nf = 0; nf < 4; nf++)
          sacc[mf][nf] = __builtin_amdgcn_mfma_f32_16x16x32_bf16(kf[mf][ks], qf[nf][ks],
                                                                 sacc[mf][nf], 0, 0, 0);
    __builtin_amdgcn_s_setprio(0);

    // prefetch K frags for next tile (coalesced: 64 lanes x 16 B contiguous)
#pragma unroll
    for (int mf = 0; mf < 2; mf++)
#pragma unroll
      for (int ks = 0; ks < 2; ks++)
        kf[mf][ks] = *(const short8*)(Kw + tn + mf * 1024 + ks * 512);

    // ---- P = exp2(sacc), packed in-register; B-frag for x32 PV is the
    //      register-local concat of the two chunk C-frags (k-permuted) ----
    short8 pbf[4];
#pragma unroll
    for (int nf = 0; nf < 4; nf++) {
      uint2v pu[2];
#pragma unroll
      for (int mf = 0; mf < 2; mf++) {
        unsigned u0 = __builtin_bit_cast(unsigned, __builtin_amdgcn_exp2f(sacc[mf][nf][0])) + 0x8000u;
        unsigned u1 = __builtin_bit_cast(unsigned, __builtin_amdgcn_exp2f(sacc[mf][nf][1])) + 0x8000u;
        unsigned u2 = __builtin_bit_cast(unsigned, __builtin_amdgcn_exp2f(sacc[mf][nf][2])) + 0x8000u;
        unsigned u3 = __builtin_bit_cast(unsigned, __builtin_amdgcn_exp2f(sacc[mf][nf][3])) + 0x8000u;
        unsigned lo = __builtin_amdgcn_perm(u1, u0, 0x07060302u);  // [bf16(e0), bf16(e1)]
        unsigned hi = __builtin_amdgcn_perm(u3, u2, 0x07060302u);  // [bf16(e2), bf16(e3)]
        pu[mf] = (uint2v){lo, hi};
      }
      pbf[nf] = __builtin_bit_cast(short8, (uint4v){pu[0][0], pu[0][1], pu[1][0], pu[1][1]});
    }

    __builtin_amdgcn_s_setprio(1);
    // ---- denominator: ones-row x32 MFMA (colsum of P over 32 kv) ----
#pragma unroll
    for (int nf = 0; nf < 4; nf++)
      dacc[nf] = __builtin_amdgcn_mfma_f32_16x16x32_bf16(ones8, pbf[nf], dacc[nf], 0, 0, 0);

    // ---- O^T += V^T . P^T over wave's 32 kv (single x32 per frag) ----
#pragma unroll
    for (int mfd = 0; mfd < 4; mfd++)
#pragma unroll
      for (int nf = 0; nf < 4; nf++)
        oacc[mfd][nf] = __builtin_amdgcn_mfma_f32_16x16x32_bf16(vf[mfd], pbf[nf],
                                                                oacc[mfd][nf], 0, 0, 0);
    __builtin_amdgcn_s_setprio(0);

    // prefetch V frags for next tile (coalesced: 64 lanes x 16 B contiguous)
#pragma unroll
    for (int mfd = 0; mfd < 4; mfd++)
      vf[mfd] = *(const short8*)(Vw + tn + mfd * 512);
  }

  // ---- cross-wave reduction: O = sum_w O_w, denom = sum_w dacc ----
  if (g == 0) {
#pragma unroll
    for (int nf = 0; nf < 4; nf++) lred[w * 64 + nf * 16 + ln] = dacc[nf][0];
  }
#pragma unroll
  for (int mfd = 0; mfd < 4; mfd++)
#pragma unroll
    for (int nf = 0; nf < 4; nf++)
      *(floatx4*)(&red[w * 4352 + (nf * 16 + ln) * 68 + mfd * 16 + g * 4]) = oacc[mfd][nf];
  __syncthreads();

  // wave w reduces+stores d-quarter [16w,16w+16) for all 64 q; lane l = q
  const int q = l;
  const float denom = lred[q] + lred[64 + q] + lred[128 + q] + lred[192 + q];
  const float linv = 1.0f / denom;
#pragma unroll
  for (int i = 0; i < 4; i++) {
    floatx4 s = (floatx4){0.f, 0.f, 0.f, 0.f};
#pragma unroll
    for (int w2 = 0; w2 < 4; w2++)
      s += *(const floatx4*)(&red[w2 * 4352 + q * 68 + w * 16 + i * 4]);
    s *= linv;
#pragma unroll
    for (int r = 0; r < 4; r++)
      Ot[(size_t)(b * D_ + w * 16 + i * 4 + r) * S_ + q0 + q] = s[r];
  }
}

// ---------------------------------------------------------------------------
// Unpack: Ot [B][D][S] f32 -> out [D][S][B] f32 (verified round 3).
// ---------------------------------------------------------------------------
__global__ __launch_bounds__(256) void unpack_o(const float* __restrict__ Ot,
                                                float* __restrict__ out) {
  const int d0 = (int)(blockIdx.x & 7) * 8;
  const int s0 = (int)(blockIdx.x >> 3) * 64;
  __shared__ float u[8 * 1024];
  const int t = threadIdx.x;
#pragma unroll
  for (int i = 0; i < 8; i++) {
    int j = i * 256 + t;
    int d = j >> 8, bb = (j >> 4) & 15, c = j & 15;
    float4 v = *(const float4*)(Ot + (size_t)(bb * D_ + d0 + d) * S_ + s0 + c * 4);
    float vv[4] = {v.x, v.y, v.z, v.w};
#pragma unroll
    for (int k = 0; k < 4; k++) {
      int si = c * 4 + k;
      int W = si * 16 + bb;
      int Wp = W ^ ((si & 15) << 2);
      u[d * 1024 + Wp] = vv[k];
    }
  }
  __syncthreads();
#pragma unroll
  for (int i = 0; i < 8; i++) {
    int j = i * 256 + t;
    int d = j >> 8, c2 = j & 255;
    int G = c2 ^ ((c2 >> 2) & 15);
    float4 v = *(const float4*)(&u[d * 1024 + G * 4]);
    *(float4*)(out + (size_t)(d0 + d) * (S_ * B_) + s0 * B_ + c2 * 4) = v;
  }
}

// ---------------------------------------------------------------------------
extern "C" void kernel_launch(void* const* d_in, const int* in_sizes, int n_in,
                              void* d_out, int out_size, void* d_ws, size_t ws_size,
                              hipStream_t stream) {
  const float* Q = (const float*)d_in[0];    // f32 [D][S][B]
  const float* K = (const float*)d_in[1];
  const float* V = (const float*)d_in[2];
  float* out = (float*)d_out;                // f32 [D][S][B]
  char* ws = (char*)d_ws;
  unsigned short* Qp = (unsigned short*)(ws);                  // 4 MB bf16, frag-ordered
  unsigned short* Kp = (unsigned short*)(ws + (4u << 20));     // 4 MB bf16, frag-ordered, pre-scaled
  unsigned short* Vt = (unsigned short*)(ws + (8u << 20));     // 4 MB bf16, k-permuted V^T
  float* Ot = (float*)(ws + (12u << 20));                      // 8 MB f32  [B][D][S]

  hipLaunchKernelGGL(pack_all, dim3(384), dim3(256), 0, stream, Q, K, V, Qp, Kp, Vt);
  hipLaunchKernelGGL(attn, dim3(512), dim3(256), 0, stream, Qp, Kp, Vt, Ot);
  hipLaunchKernelGGL(unpack_o, dim3(256), dim3(256), 0, stream, Ot, out);
}